// Round 13
// baseline (213.239 us; speedup 1.0000x reference)
//
#include <hip/hip_runtime.h>
#include <math.h>

typedef __bf16 bf16x8 __attribute__((ext_vector_type(8)));
typedef __bf16 bf16x4 __attribute__((ext_vector_type(4)));
typedef float  f32x4  __attribute__((ext_vector_type(4)));

// async global->LDS, 16B per lane; LDS dest = wave-uniform base + lane*16,
// global source is PER-LANE (enables source-side swizzle, LDS stays linear)
__device__ __forceinline__ void gload16(const float* g, float* l)
{
    __builtin_amdgcn_global_load_lds(
        (const __attribute__((address_space(1))) void*)g,
        (__attribute__((address_space(3))) void*)l, 16, 0, 0);
}

// ---------------------------------------------------------------------------
// cvt: fp32 -> bf16 for the 4 weight matrices (512x512 each)
// ---------------------------------------------------------------------------
__global__ __launch_bounds__(256)
void cvt_w(const float* __restrict__ w0, const float* __restrict__ w1,
           const float* __restrict__ w2, const float* __restrict__ w3,
           __bf16* __restrict__ d0, __bf16* __restrict__ d1,
           __bf16* __restrict__ d2, __bf16* __restrict__ d3)
{
    const int y = blockIdx.y;
    const float* s = (y == 0) ? w0 : (y == 1) ? w1 : (y == 2) ? w2 : w3;
    __bf16*      d = (y == 0) ? d0 : (y == 1) ? d1 : (y == 2) ? d2 : d3;
    const int i = blockIdx.x * 256 + threadIdx.x;
    float4 a = *(const float4*)(s + (size_t)i * 8);
    float4 b = *(const float4*)(s + (size_t)i * 8 + 4);
    bf16x8 v;
    v[0] = (__bf16)a.x; v[1] = (__bf16)a.y; v[2] = (__bf16)a.z; v[3] = (__bf16)a.w;
    v[4] = (__bf16)b.x; v[5] = (__bf16)b.y; v[6] = (__bf16)b.z; v[7] = (__bf16)b.w;
    *(bf16x8*)(d + (size_t)i * 8) = v;
}

// ---------------------------------------------------------------------------
// Fused QKV projection, z-merged (R8-proven). Tile 64x128, grid (64,4).
// ---------------------------------------------------------------------------
__global__ __launch_bounds__(256, 2)
void qkv_proj(const float* __restrict__ X,
              const __bf16* __restrict__ Wqb, const __bf16* __restrict__ Wkb,
              const __bf16* __restrict__ Wvb,
              const float* __restrict__ bq, const float* __restrict__ bk,
              const float* __restrict__ bv,
              __bf16* __restrict__ qTb, __bf16* __restrict__ kTb,
              __bf16* __restrict__ vTb)
{
    const int tid  = threadIdx.x;
    const int w    = tid >> 6;
    const int lane = tid & 63;
    const int lq   = lane & 15;
    const int quad = lane >> 4;
    const int n0    = blockIdx.x * 64 + (w >> 1) * 32;
    const int obase = blockIdx.y * 128 + (w & 1) * 64;

    const __bf16* const Wz[3] = { Wqb, Wkb, Wvb };

    f32x4 acc[3][2][4] = {};
    for (int k0 = 0; k0 < 512; k0 += 32) {
        bf16x8 af[2];
#pragma unroll
        for (int m = 0; m < 2; m++) {
            const float* xp = X + (size_t)(n0 + m * 16 + lq) * 512 + k0 + quad * 8;
            float4 x0 = *(const float4*)xp;
            float4 x1 = *(const float4*)(xp + 4);
            bf16x8 v;
            v[0] = (__bf16)x0.x; v[1] = (__bf16)x0.y; v[2] = (__bf16)x0.z; v[3] = (__bf16)x0.w;
            v[4] = (__bf16)x1.x; v[5] = (__bf16)x1.y; v[6] = (__bf16)x1.z; v[7] = (__bf16)x1.w;
            af[m] = v;
        }
#pragma unroll
        for (int z = 0; z < 3; z++) {
            bf16x8 bfr[4];
#pragma unroll
            for (int nn = 0; nn < 4; nn++)
                bfr[nn] = *(const bf16x8*)(Wz[z] + (size_t)(obase + nn * 16 + lq) * 512 + k0 + quad * 8);
#pragma unroll
            for (int m = 0; m < 2; m++)
#pragma unroll
                for (int nn = 0; nn < 4; nn++)
                    acc[z][m][nn] = __builtin_amdgcn_mfma_f32_16x16x32_bf16(af[m], bfr[nn], acc[z][m][nn], 0, 0, 0);
        }
    }

    const float* const ba[3] = { bq, bk, bv };
    const float scaling = 0.17677669529663687f;
#pragma unroll
    for (int z = 0; z < 3; z++)
#pragma unroll
        for (int m = 0; m < 2; m++)
#pragma unroll
            for (int nn = 0; nn < 4; nn++)
#pragma unroll
                for (int r = 0; r < 4; r++) {
                    const int n = n0 + m * 16 + quad * 4 + r;
                    const int o = obase + nn * 16 + lq;
                    float val = acc[z][m][nn][r] + ba[z][o];
                    const int t = n >> 2, b = n & 3;
                    const int h = o >> 5, d = o & 31;
                    const int bh = b * 16 + h;
                    if (z == 0)
                        qTb[(((size_t)bh * 1024 + t) << 5) + d] = (__bf16)(val * scaling);
                    else if (z == 1)
                        kTb[(((size_t)bh * 1024 + t) << 5) + d] = (__bf16)val;
                    else
                        vTb[(((size_t)bh * 32 + d) << 10) + t] = (__bf16)val;
                }
}

// ---------------------------------------------------------------------------
// Out projection: A bf16 [4096][512], W bf16, out fp32 + bias. Tile 64x128.
// ---------------------------------------------------------------------------
__global__ __launch_bounds__(256)
void out_proj(const __bf16* __restrict__ A, const __bf16* __restrict__ Wb,
              const float* __restrict__ bias, float* __restrict__ out)
{
    const int tid  = threadIdx.x;
    const int w    = tid >> 6;
    const int lane = tid & 63;
    const int lq   = lane & 15;
    const int quad = lane >> 4;
    const int n0    = blockIdx.x * 64 + (w >> 1) * 32;
    const int obase = blockIdx.y * 128 + (w & 1) * 64;

    f32x4 acc[2][4] = {};
    for (int k0 = 0; k0 < 512; k0 += 32) {
        bf16x8 af[2], bfr[4];
#pragma unroll
        for (int m = 0; m < 2; m++)
            af[m] = *(const bf16x8*)(A + (size_t)(n0 + m * 16 + lq) * 512 + k0 + quad * 8);
#pragma unroll
        for (int nn = 0; nn < 4; nn++)
            bfr[nn] = *(const bf16x8*)(Wb + (size_t)(obase + nn * 16 + lq) * 512 + k0 + quad * 8);
#pragma unroll
        for (int m = 0; m < 2; m++)
#pragma unroll
            for (int nn = 0; nn < 4; nn++)
                acc[m][nn] = __builtin_amdgcn_mfma_f32_16x16x32_bf16(af[m], bfr[nn], acc[m][nn], 0, 0, 0);
    }
#pragma unroll
    for (int m = 0; m < 2; m++)
#pragma unroll
        for (int nn = 0; nn < 4; nn++)
#pragma unroll
            for (int r = 0; r < 4; r++) {
                const int n = n0 + m * 16 + quad * 4 + r;
                const int o = obase + nn * 16 + lq;
                out[(size_t)n * 512 + o] = acc[m][nn][r] + bias[o];
            }
}

// ---------------------------------------------------------------------------
// MFMA attention = R9 geometry (best measured, 145.1us) + PER-WAVE LDS bias
// staging. Block = (32 t-rows, b, 8-head half); grid (32,4,2) = 256 = 1/CU.
//
// THE POINT OF THIS ROUND: request granularity. The bias C-operand loads
// were 16 requests x 64B at 4-KB stride per instruction (the one stream
// that is request-rate-inefficient; K is fully coalesced). Each wave now
// stages ITS OWN 8-KB bias slice via global_load_lds at 1 KB contiguous
// per instruction (8 x 128B full-line requests) -- half the requests, all
// full-line. Unlike R10 (block-wide rendezvous, regressed), staging is
// wave-private: single 8KB slot/wave, counted vmcnt(1) (leaves only the
// attnb store in flight) + same-wave lgkm. NO extra barriers.
// Source-side XOR swizzle + read formula lifted from the R0 kernel
// (refcheck-proven): granule c stored at c^(row&7); read
// slot[lq*128 + ((j*4+quad)^(lq&7))*4].
// Liveness: cj read to regs (+lgkm0) BEFORE stage(i+1) overwrites the slot.
// VMEM order/iter: [vmcnt(1)][cj ds_read][K/V if ts==0][stage(i+1)+qa(i+1)
// youngest][QK][exp/P/PV][lgkm barrier][reduce+store][avg fold].
// ---------------------------------------------------------------------------
__global__ __launch_bounds__(512)
void attn_mfma(const __bf16* __restrict__ qTb, const __bf16* __restrict__ kTb,
               const __bf16* __restrict__ vTb, const float* __restrict__ bias,
               const int* __restrict__ mask, __bf16* __restrict__ attnb,
               float* __restrict__ avgf, __bf16* __restrict__ p1)
{
    // [0,8448): Op[2][8][528]  [8448,8704): red[2][8][16]
    // [8704,17408): P bf16 [8][16*136]  [17408,33792): stage [8][2048]
    __shared__ float smem[33792];
    float* const Op0  = smem;
    float* const red0 = &smem[8448];
    __bf16* const Pbase = (__bf16*)&smem[8704];

    const int tid  = threadIdx.x;
    const int w    = tid >> 6;
    const int lane = tid & 63;
    const int lq   = lane & 15;
    const int quad = lane >> 4;
    const int srow = lane >> 5;          // staging: row-half within pair
    const int schk = lane & 31;          // staging: stored granule index

    // bijective XCD swizzle (R9-verified)
    const int bid = blockIdx.z * 128 + blockIdx.y * 32 + blockIdx.x;
    const int swz = (bid & 7) * 32 + (bid >> 3);
    const int t0  = (swz & 31) * 32;     // 32-row t-supertile
    const int b   = (swz >> 5) & 3;
    const int z   = swz >> 7;            // head half
    const int sbase = w * 128;

    __bf16* const Pw  = Pbase + w * 2176;     // 16*136 bf16 per wave
    float*  const slotB = &smem[17408 + w * 2048];  // per-wave 8KB stage slot

    // pack 32 mask bits (s = sbase + j*16 + quad*4 + r)
    unsigned mbits = 0;
    {
        const int* mp = mask + b * 1024 + sbase + quad * 4;
#pragma unroll
        for (int j = 0; j < 8; j++) {
            int4 m4 = *(const int4*)(mp + j * 16);
            mbits |= (unsigned)(m4.x != 0) << (j * 4 + 0);
            mbits |= (unsigned)(m4.y != 0) << (j * 4 + 1);
            mbits |= (unsigned)(m4.z != 0) << (j * 4 + 2);
            mbits |= (unsigned)(m4.w != 0) << (j * 4 + 3);
        }
    }

    // bases: this block's 8 heads (z*8..z*8+7), t-rows t0..t0+31
    const float* const biasW = bias + (((size_t)(b * 16 + z * 8)) << 20) +
                               (size_t)t0 * 1024 + sbase;
    const __bf16* const qpW = qTb + (((size_t)((b * 16 + z * 8) * 1024 + t0)) << 5) +
                              lq * 32 + quad * 8;
    const __bf16* const kp0 = kTb + ((size_t)(b * 16 + z * 8) << 15);
    const __bf16* const vp0 = vTb + ((size_t)(b * 16 + z * 8) << 15);

    // prologue: stage iter-0 slice (head 0, ts 0); qa issued AFTER (younger,
    // so iter-0's vmcnt(1) leaves qa and fully drains the stage)
#pragma unroll
    for (int k = 0; k < 8; k++) {
        const int row = 2 * k + srow;
        const int c   = schk ^ (row & 7);
        gload16(biasW + (size_t)row * 1024 + c * 4, slotB + k * 256);
    }
    bf16x8 qa = *(const bf16x8*)qpW;

    float avg0[32] = {}, avg1[32] = {};
    bf16x8 kb[8];            // persist across the two t-subtiles of a head
    bf16x8 v0r[4], v1r[4];

    auto body = [&](int hh, int ts, float (&avg)[32]) {
        const int i  = hh * 2 + ts;
        const int in = (i + 1) & 15;
        float* const Op  = Op0  + ts * 4224;
        float* const red = red0 + ts * 128;

        // a: drain stage(i) -- leaves only the attnb store (steady state)
        __builtin_amdgcn_sched_barrier(0);
        asm volatile("s_waitcnt vmcnt(1)" ::: "memory");
        __builtin_amdgcn_sched_barrier(0);

        // b: cj from the wave's staged slice; lgkm0 so the slot is reusable
        f32x4 cj[8];
#pragma unroll
        for (int j = 0; j < 8; j++)
            cj[j] = *(const f32x4*)&slotB[lq * 128 + (((j * 4 + quad) ^ (lq & 7)) << 2)];
        asm volatile("s_waitcnt lgkmcnt(0)" ::: "memory");
        __builtin_amdgcn_sched_barrier(0);

        // c: K/V once per head (ts==0), reused at ts==1
        if (ts == 0) {
            const __bf16* kp = kp0 + ((size_t)hh << 15);
            const __bf16* vp = vp0 + ((size_t)hh << 15);
#pragma unroll
            for (int j = 0; j < 8; j++)
                kb[j] = *(const bf16x8*)(kp + (size_t)(sbase + j * 16 + lq) * 32 + quad * 8);
#pragma unroll
            for (int ks = 0; ks < 4; ks++) {
                v0r[ks] = *(const bf16x8*)(vp + (size_t)lq * 1024 + sbase + ks * 32 + quad * 8);
                v1r[ks] = *(const bf16x8*)(vp + (size_t)(16 + lq) * 1024 + sbase + ks * 32 + quad * 8);
            }
        }
        __builtin_amdgcn_sched_barrier(0);

        // d: hold qa(i), then stage(i+1) + qa(i+1) = youngest VMEM
        bf16x8 qc = qa;
        {
            const float* src = biasW + ((size_t)(in >> 1) << 20) + ((in & 1) << 14);
#pragma unroll
            for (int k = 0; k < 8; k++) {
                const int row = 2 * k + srow;
                const int c   = schk ^ (row & 7);
                gload16(src + (size_t)row * 1024 + c * 4, slotB + k * 256);
            }
            qa = *(const bf16x8*)(qpW + ((size_t)(in >> 1) << 15) + ((in & 1) << 9));
        }
        __builtin_amdgcn_sched_barrier(0);

        // e: QK (kb waits drain K/V at most; stage/qa prefetch stay in flight)
        f32x4 acc[8];
#pragma unroll
        for (int j = 0; j < 8; j++)
            acc[j] = __builtin_amdgcn_mfma_f32_16x16x32_bf16(kb[j], qc, cj[j], 0, 0, 0);
        __builtin_amdgcn_sched_barrier(0);

        // f: exp (no max pass; scores bounded) + mask + row partial sum
        float sm = 0.f;
#pragma unroll
        for (int j = 0; j < 8; j++)
#pragma unroll
            for (int r = 0; r < 4; r++) {
                float p = __expf(acc[j][r]);
                p = ((mbits >> (j * 4 + r)) & 1u) ? 0.f : p;
                acc[j][r] = p;
                sm += p;
            }
        sm += __shfl_xor(sm, 16);
        sm += __shfl_xor(sm, 32);

        // g: unnormalized bf16 P into per-wave LDS (same-wave use only)
#pragma unroll
        for (int j = 0; j < 8; j++) {
            bf16x4 pv;
            pv[0] = (__bf16)acc[j][0]; pv[1] = (__bf16)acc[j][1];
            pv[2] = (__bf16)acc[j][2]; pv[3] = (__bf16)acc[j][3];
            *(bf16x4*)&Pw[lq * 136 + j * 16 + quad * 4] = pv;
        }
        if (lane < 16) red[w * 16 + lane] = sm;

        // h: PV (P via lgkm; V regs -- their waits are older than the stage)
        f32x4 o0 = {0.f, 0.f, 0.f, 0.f}, o1 = {0.f, 0.f, 0.f, 0.f};
#pragma unroll
        for (int ks = 0; ks < 4; ks++) {
            bf16x8 pa = *(const bf16x8*)&Pw[lq * 136 + ks * 32 + quad * 8];
            o0 = __builtin_amdgcn_mfma_f32_16x16x32_bf16(pa, v0r[ks], o0, 0, 0, 0);
            o1 = __builtin_amdgcn_mfma_f32_16x16x32_bf16(pa, v1r[ks], o1, 0, 0, 0);
        }
#pragma unroll
        for (int r = 0; r < 4; r++) {
            Op[w * 528 + (quad * 4 + r) * 33 + lq]      = o0[r];
            Op[w * 528 + (quad * 4 + r) * 33 + 16 + lq] = o1[r];
        }

        // i: raw barrier, LDS-only drain; stage/qa prefetch stay in flight
        __builtin_amdgcn_sched_barrier(0);
        asm volatile("s_waitcnt lgkmcnt(0)" ::: "memory");
        __builtin_amdgcn_s_barrier();
        __builtin_amdgcn_sched_barrier(0);

        // j: cross-wave reduce, normalized O write (the only VMEM younger
        // than the stage -> vmcnt(1) at next iter's step a)
        {
            const int t = tid >> 5, d = tid & 31;
            float s = 0.f, o = 0.f;
#pragma unroll
            for (int w2 = 0; w2 < 8; w2++) s += red[w2 * 16 + t];
#pragma unroll
            for (int w2 = 0; w2 < 8; w2++) o += Op[w2 * 528 + t * 33 + d];
            attnb[((size_t)(t0 + ts * 16 + t) * 4 + b) * 512 + (z * 8 + hh) * 32 + d] =
                (__bf16)(o / s);
        }

        // k: inv for this lane's rows (t = ts*16+lq) + avg fold
        float s_all = 0.f;
#pragma unroll
        for (int w2 = 0; w2 < 8; w2++) s_all += red[w2 * 16 + lq];
        const float inv = 1.0f / s_all;
#pragma unroll
        for (int j = 0; j < 8; j++)
#pragma unroll
            for (int r = 0; r < 4; r++)
                avg[j * 4 + r] += acc[j][r] * inv;
    };

    for (int hh = 0; hh < 8; hh++) {
        body(hh, 0, avg0);
        body(hh, 1, avg1);
    }

    // head-mean stores for both t-subtiles: z=0 fp32 direct, z=1 bf16 partial
#pragma unroll
    for (int ts = 0; ts < 2; ts++) {
        const float* avg = ts ? avg1 : avg0;
        const size_t rowbase = ((size_t)(b * 1024 + t0 + ts * 16 + lq) << 10) +
                               sbase + quad * 4;
        if (z == 0) {
            float* ap = avgf + rowbase;
#pragma unroll
            for (int j = 0; j < 8; j++) {
                f32x4 v = { avg[j * 4 + 0] * 0.0625f, avg[j * 4 + 1] * 0.0625f,
                            avg[j * 4 + 2] * 0.0625f, avg[j * 4 + 3] * 0.0625f };
                *(f32x4*)(ap + j * 16) = v;
            }
        } else {
            __bf16* pp = p1 + rowbase;
#pragma unroll
            for (int j = 0; j < 8; j++) {
                bf16x4 v;
                v[0] = (__bf16)(avg[j * 4 + 0] * 0.0625f);
                v[1] = (__bf16)(avg[j * 4 + 1] * 0.0625f);
                v[2] = (__bf16)(avg[j * 4 + 2] * 0.0625f);
                v[3] = (__bf16)(avg[j * 4 + 3] * 0.0625f);
                *(bf16x4*)(pp + j * 16) = v;
            }
        }
    }
}

// avg_out += p1 (bf16 partial). 2048 blocks * 256 thr * 8 = 4194304
__global__ __launch_bounds__(256)
void avg_add(float* __restrict__ avg, const __bf16* __restrict__ p1)
{
    const size_t i = ((size_t)blockIdx.x * 256 + threadIdx.x) * 8;
    bf16x8 a = *(const bf16x8*)(p1 + i);
    float4 lo = *(float4*)(avg + i);
    float4 hi = *(float4*)(avg + i + 4);
    lo.x += (float)a[0]; lo.y += (float)a[1];
    lo.z += (float)a[2]; lo.w += (float)a[3];
    hi.x += (float)a[4]; hi.y += (float)a[5];
    hi.z += (float)a[6]; hi.w += (float)a[7];
    *(float4*)(avg + i)     = lo;
    *(float4*)(avg + i + 4) = hi;
}

// ---------------------------------------------------------------------------
extern "C" void kernel_launch(void* const* d_in, const int* in_sizes, int n_in,
                              void* d_out, int out_size, void* d_ws, size_t ws_size,
                              hipStream_t stream)
{
    const float* query     = (const float*)d_in[0];
    const float* attn_bias = (const float*)d_in[1];
    const int*   mask      = (const int*)d_in[2];
    const float* q_w       = (const float*)d_in[3];
    const float* q_b       = (const float*)d_in[4];
    const float* k_w       = (const float*)d_in[5];
    const float* k_b       = (const float*)d_in[6];
    const float* v_w       = (const float*)d_in[7];
    const float* v_b       = (const float*)d_in[8];
    const float* out_w     = (const float*)d_in[9];
    const float* out_b     = (const float*)d_in[10];

    float* out     = (float*)d_out;                 // [1024,4,512]
    float* avg_out = out + (size_t)2097152;         // [4,1024,1024]

    char* wsb = (char*)d_ws;
    __bf16* Wqb   = (__bf16*)(wsb);                         // 512 KB
    __bf16* Wkb   = (__bf16*)(wsb + ((size_t)512 << 10));
    __bf16* Wvb   = (__bf16*)(wsb + ((size_t)1 << 20));
    __bf16* Wob   = (__bf16*)(wsb + ((size_t)1 << 20) + ((size_t)512 << 10));
    __bf16* qTb   = (__bf16*)(wsb + ((size_t)2  << 20));    // 4 MB [64][1024][32]
    __bf16* kTb   = (__bf16*)(wsb + ((size_t)6  << 20));    // 4 MB [64][1024][32]
    __bf16* vTb   = (__bf16*)(wsb + ((size_t)10 << 20));    // 4 MB [64][32][1024]
    __bf16* attnb = (__bf16*)(wsb + ((size_t)14 << 20));    // 4 MB [4096][512]
    __bf16* p1    = (__bf16*)(wsb + ((size_t)18 << 20));    // 8 MB

    cvt_w<<<dim3(128, 4), dim3(256), 0, stream>>>(
        q_w, k_w, v_w, out_w, Wqb, Wkb, Wvb, Wob);

    qkv_proj<<<dim3(64, 4), dim3(256), 0, stream>>>(
        query, Wqb, Wkb, Wvb, q_b, k_b, v_b, qTb, kTb, vTb);

    attn_mfma<<<dim3(32, 4, 2), dim3(512), 0, stream>>>(
        qTb, kTb, vTb, attn_bias, mask, attnb, avg_out, p1);

    avg_add<<<dim3(2048), dim3(256), 0, stream>>>(avg_out, p1);

    out_proj<<<dim3(64, 4), dim3(256), 0, stream>>>(attnb, Wob, out_b, out);
}

// Round 14
// 141.475 us; speedup vs baseline: 1.5073x; 1.5073x over previous
//
#include <hip/hip_runtime.h>
#include <math.h>

typedef __bf16 bf16x8 __attribute__((ext_vector_type(8)));
typedef __bf16 bf16x4 __attribute__((ext_vector_type(4)));
typedef float  f32x4  __attribute__((ext_vector_type(4)));

// ---------------------------------------------------------------------------
// cvt: fp32 -> bf16 for the 4 weight matrices (512x512 each)
// ---------------------------------------------------------------------------
__global__ __launch_bounds__(256)
void cvt_w(const float* __restrict__ w0, const float* __restrict__ w1,
           const float* __restrict__ w2, const float* __restrict__ w3,
           __bf16* __restrict__ d0, __bf16* __restrict__ d1,
           __bf16* __restrict__ d2, __bf16* __restrict__ d3)
{
    const int y = blockIdx.y;
    const float* s = (y == 0) ? w0 : (y == 1) ? w1 : (y == 2) ? w2 : w3;
    __bf16*      d = (y == 0) ? d0 : (y == 1) ? d1 : (y == 2) ? d2 : d3;
    const int i = blockIdx.x * 256 + threadIdx.x;
    float4 a = *(const float4*)(s + (size_t)i * 8);
    float4 b = *(const float4*)(s + (size_t)i * 8 + 4);
    bf16x8 v;
    v[0] = (__bf16)a.x; v[1] = (__bf16)a.y; v[2] = (__bf16)a.z; v[3] = (__bf16)a.w;
    v[4] = (__bf16)b.x; v[5] = (__bf16)b.y; v[6] = (__bf16)b.z; v[7] = (__bf16)b.w;
    *(bf16x8*)(d + (size_t)i * 8) = v;
}

// ---------------------------------------------------------------------------
// Fused QKV projection, z-merged (R8-proven, +9us): one block computes Q, K
// and V for its tile; X loaded once per k-chunk feeds all three MFMA sets.
// ---------------------------------------------------------------------------
__global__ __launch_bounds__(256, 2)
void qkv_proj(const float* __restrict__ X,
              const __bf16* __restrict__ Wqb, const __bf16* __restrict__ Wkb,
              const __bf16* __restrict__ Wvb,
              const float* __restrict__ bq, const float* __restrict__ bk,
              const float* __restrict__ bv,
              __bf16* __restrict__ qTb, __bf16* __restrict__ kTb,
              __bf16* __restrict__ vTb)
{
    const int tid  = threadIdx.x;
    const int w    = tid >> 6;
    const int lane = tid & 63;
    const int lq   = lane & 15;
    const int quad = lane >> 4;
    const int n0    = blockIdx.x * 64 + (w >> 1) * 32;
    const int obase = blockIdx.y * 128 + (w & 1) * 64;

    const __bf16* const Wz[3] = { Wqb, Wkb, Wvb };

    f32x4 acc[3][2][4] = {};
    for (int k0 = 0; k0 < 512; k0 += 32) {
        bf16x8 af[2];
#pragma unroll
        for (int m = 0; m < 2; m++) {
            const float* xp = X + (size_t)(n0 + m * 16 + lq) * 512 + k0 + quad * 8;
            float4 x0 = *(const float4*)xp;
            float4 x1 = *(const float4*)(xp + 4);
            bf16x8 v;
            v[0] = (__bf16)x0.x; v[1] = (__bf16)x0.y; v[2] = (__bf16)x0.z; v[3] = (__bf16)x0.w;
            v[4] = (__bf16)x1.x; v[5] = (__bf16)x1.y; v[6] = (__bf16)x1.z; v[7] = (__bf16)x1.w;
            af[m] = v;
        }
#pragma unroll
        for (int z = 0; z < 3; z++) {
            bf16x8 bfr[4];
#pragma unroll
            for (int nn = 0; nn < 4; nn++)
                bfr[nn] = *(const bf16x8*)(Wz[z] + (size_t)(obase + nn * 16 + lq) * 512 + k0 + quad * 8);
#pragma unroll
            for (int m = 0; m < 2; m++)
#pragma unroll
                for (int nn = 0; nn < 4; nn++)
                    acc[z][m][nn] = __builtin_amdgcn_mfma_f32_16x16x32_bf16(af[m], bfr[nn], acc[z][m][nn], 0, 0, 0);
        }
    }

    const float* const ba[3] = { bq, bk, bv };
    const float scaling = 0.17677669529663687f;
#pragma unroll
    for (int z = 0; z < 3; z++)
#pragma unroll
        for (int m = 0; m < 2; m++)
#pragma unroll
            for (int nn = 0; nn < 4; nn++)
#pragma unroll
                for (int r = 0; r < 4; r++) {
                    const int n = n0 + m * 16 + quad * 4 + r;
                    const int o = obase + nn * 16 + lq;
                    float val = acc[z][m][nn][r] + ba[z][o];
                    const int t = n >> 2, b = n & 3;
                    const int h = o >> 5, d = o & 31;
                    const int bh = b * 16 + h;
                    if (z == 0)
                        qTb[(((size_t)bh * 1024 + t) << 5) + d] = (__bf16)(val * scaling);
                    else if (z == 1)
                        kTb[(((size_t)bh * 1024 + t) << 5) + d] = (__bf16)val;
                    else
                        vTb[(((size_t)bh * 32 + d) << 10) + t] = (__bf16)val;
                }
}

// ---------------------------------------------------------------------------
// Out projection (y<4) with fused avg merge (y>=4, replaces avg_add launch).
// ---------------------------------------------------------------------------
__global__ __launch_bounds__(256)
void out_proj(const __bf16* __restrict__ A, const __bf16* __restrict__ Wb,
              const float* __restrict__ bias, float* __restrict__ out,
              float* __restrict__ avg, const __bf16* __restrict__ p1)
{
    if (blockIdx.y >= 4) {
        // avg_out += p1 (bf16 partial). (64x32) blocks x 256 thr x 8 = 4194304
        const size_t i = ((size_t)((blockIdx.y - 4) * 64 + blockIdx.x) * 256 +
                          threadIdx.x) * 8;
        bf16x8 a = *(const bf16x8*)(p1 + i);
        float4 lo = *(float4*)(avg + i);
        float4 hi = *(float4*)(avg + i + 4);
        lo.x += (float)a[0]; lo.y += (float)a[1];
        lo.z += (float)a[2]; lo.w += (float)a[3];
        hi.x += (float)a[4]; hi.y += (float)a[5];
        hi.z += (float)a[6]; hi.w += (float)a[7];
        *(float4*)(avg + i)     = lo;
        *(float4*)(avg + i + 4) = hi;
        return;
    }

    const int tid  = threadIdx.x;
    const int w    = tid >> 6;
    const int lane = tid & 63;
    const int lq   = lane & 15;
    const int quad = lane >> 4;
    const int n0    = blockIdx.x * 64 + (w >> 1) * 32;
    const int obase = blockIdx.y * 128 + (w & 1) * 64;

    f32x4 acc[2][4] = {};
    for (int k0 = 0; k0 < 512; k0 += 32) {
        bf16x8 af[2], bfr[4];
#pragma unroll
        for (int m = 0; m < 2; m++)
            af[m] = *(const bf16x8*)(A + (size_t)(n0 + m * 16 + lq) * 512 + k0 + quad * 8);
#pragma unroll
        for (int nn = 0; nn < 4; nn++)
            bfr[nn] = *(const bf16x8*)(Wb + (size_t)(obase + nn * 16 + lq) * 512 + k0 + quad * 8);
#pragma unroll
        for (int m = 0; m < 2; m++)
#pragma unroll
            for (int nn = 0; nn < 4; nn++)
                acc[m][nn] = __builtin_amdgcn_mfma_f32_16x16x32_bf16(af[m], bfr[nn], acc[m][nn], 0, 0, 0);
    }
#pragma unroll
    for (int m = 0; m < 2; m++)
#pragma unroll
        for (int nn = 0; nn < 4; nn++)
#pragma unroll
            for (int r = 0; r < 4; r++) {
                const int n = n0 + m * 16 + quad * 4 + r;
                const int o = obase + nn * 16 + lq;
                out[(size_t)n * 512 + o] = acc[m][nn][r] + bias[o];
            }
}

// ---------------------------------------------------------------------------
// MFMA attention = R9 (best measured, 145.1us) with ONE register-diet edit:
// the avg fold re-reads P from this wave's LDS slice after the barrier
// instead of keeping acc[8] (32 VGPRs) alive through PV+barrier+reduce.
// Rationale: every attn variant is pinned at 128 VGPRs by the toolchain;
// R9's live set (~200) spills, and the cold post-PV acc span is a prime
// spill victim -- freeing it cuts per-body fill traffic with ~zero cost
// (8 same-address ds_reads; avg uses the SAME bf16-rounded P that PV
// already consumes). Everything else is byte-identical to R9.
// ---------------------------------------------------------------------------
__global__ __attribute__((amdgpu_waves_per_eu(2, 2))) __launch_bounds__(512)
void attn_mfma(const __bf16* __restrict__ qTb, const __bf16* __restrict__ kTb,
               const __bf16* __restrict__ vTb, const float* __restrict__ bias,
               const int* __restrict__ mask, __bf16* __restrict__ attnb,
               float* __restrict__ avgf, __bf16* __restrict__ p1)
{
    // [0,8448): Op[2][8][528]  [8448,8704): red[2][8][16]
    // [8704,17408): P bf16 [8][16*136].  Padded >80KB (R7/R9 environment).
    __shared__ float smem[20800];
    float* const Op0  = smem;
    float* const red0 = &smem[8448];
    __bf16* const Pbase = (__bf16*)&smem[8704];

    const int tid  = threadIdx.x;
    const int w    = tid >> 6;
    const int lane = tid & 63;
    const int lq   = lane & 15;
    const int quad = lane >> 4;

    // bijective XCD swizzle (R9-verified)
    const int bid = blockIdx.z * 128 + blockIdx.y * 32 + blockIdx.x;
    const int swz = (bid & 7) * 32 + (bid >> 3);
    const int t0  = (swz & 31) * 32;       // 32-row t-supertile
    const int b   = (swz >> 5) & 3;
    const int z   = swz >> 7;              // head half
    const int sbase = w * 128;

    __bf16* const Pw = Pbase + w * 2176;   // 16*136 bf16 per wave

    // pack 32 mask bits (s = sbase + j*16 + quad*4 + r); shared by both ts
    unsigned mbits = 0;
    {
        const int* mp = mask + b * 1024 + sbase + quad * 4;
#pragma unroll
        for (int j = 0; j < 8; j++) {
            int4 m4 = *(const int4*)(mp + j * 16);
            mbits |= (unsigned)(m4.x != 0) << (j * 4 + 0);
            mbits |= (unsigned)(m4.y != 0) << (j * 4 + 1);
            mbits |= (unsigned)(m4.z != 0) << (j * 4 + 2);
            mbits |= (unsigned)(m4.w != 0) << (j * 4 + 3);
        }
    }

    // bases for this block's 8 heads (z*8 .. z*8+7), t-rows t0..t0+31
    const float* const bb = bias + (((size_t)(b * 16 + z * 8)) << 20) +
                            (((size_t)(t0 + lq)) << 10) + sbase + quad * 4;
    const __bf16* const qp0 = qTb + (((size_t)((b * 16 + z * 8) * 1024 + t0)) << 5) +
                              lq * 32 + quad * 8;
    const __bf16* const kp0 = kTb + ((size_t)(b * 16 + z * 8) << 15);
    const __bf16* const vp0 = vTb + ((size_t)(b * 16 + z * 8) << 15);

    // prologue: (head 0, ts 0) Q + bias into registers
    bf16x8 qa = *(const bf16x8*)qp0;
    f32x4 cj[8];
#pragma unroll
    for (int j = 0; j < 8; j++) cj[j] = *(const f32x4*)(bb + j * 16);

    float avg0[32] = {}, avg1[32] = {};
    bf16x8 kb[8];            // persist across the two t-subtiles of a head
    bf16x8 v0r[4], v1r[4];

    // body for one (head, t-subtile); ts is a call-site literal.
    auto body = [&](int hh, int ts, float (&avg)[32]) {
        float* const Op  = Op0  + ts * 4224;       // ts alternates 0/1
        float* const red = red0 + ts * 128;

        // K/V for this head: loaded once (ts==0), reused at ts==1.
        if (ts == 0) {
            const __bf16* kp = kp0 + ((size_t)hh << 15);
            const __bf16* vp = vp0 + ((size_t)hh << 15);
#pragma unroll
            for (int j = 0; j < 8; j++)
                kb[j] = *(const bf16x8*)(kp + (size_t)(sbase + j * 16 + lq) * 32 + quad * 8);
#pragma unroll
            for (int ks = 0; ks < 4; ks++) {
                v0r[ks] = *(const bf16x8*)(vp + (size_t)lq * 1024 + sbase + ks * 32 + quad * 8);
                v1r[ks] = *(const bf16x8*)(vp + (size_t)(16 + lq) * 1024 + sbase + ks * 32 + quad * 8);
            }
        }
        __builtin_amdgcn_sched_barrier(0);

        // QK: bias C-operands from registers (prefetched last iteration)
        f32x4 acc[8];
#pragma unroll
        for (int j = 0; j < 8; j++)
            acc[j] = __builtin_amdgcn_mfma_f32_16x16x32_bf16(kb[j], qa, cj[j], 0, 0, 0);
        __builtin_amdgcn_sched_barrier(0);

        // prefetch next iteration's Q + bias (youngest VMEM; wraps benignly)
        {
            const int hn  = (ts == 0) ? hh : ((hh + 1) & 7);
            const int tsn = ts ^ 1;
            qa = *(const bf16x8*)(qp0 + ((size_t)hn << 15) + (tsn << 9));
            const float* bn = bb + ((size_t)hn << 20) + (tsn << 14);
#pragma unroll
            for (int j = 0; j < 8; j++) cj[j] = *(const f32x4*)(bn + j * 16);
        }
        __builtin_amdgcn_sched_barrier(0);

        // exp (no max pass; scores bounded) + mask + row partial sum
        float sm = 0.f;
#pragma unroll
        for (int j = 0; j < 8; j++)
#pragma unroll
            for (int r = 0; r < 4; r++) {
                float p = __expf(acc[j][r]);
                p = ((mbits >> (j * 4 + r)) & 1u) ? 0.f : p;
                acc[j][r] = p;
                sm += p;
            }
        sm += __shfl_xor(sm, 16);
        sm += __shfl_xor(sm, 32);

        // unnormalized bf16 P into per-wave LDS region (same-wave use only).
        // acc DIES here -- the avg fold below re-reads P from LDS.
#pragma unroll
        for (int j = 0; j < 8; j++) {
            bf16x4 pv;
            pv[0] = (__bf16)acc[j][0]; pv[1] = (__bf16)acc[j][1];
            pv[2] = (__bf16)acc[j][2]; pv[3] = (__bf16)acc[j][3];
            *(bf16x4*)&Pw[lq * 136 + j * 16 + quad * 4] = pv;
        }
        if (lane < 16) red[w * 16 + lane] = sm;

        // PV: P from LDS (lgkmcnt only), V in registers
        f32x4 o0 = {0.f, 0.f, 0.f, 0.f}, o1 = {0.f, 0.f, 0.f, 0.f};
#pragma unroll
        for (int ks = 0; ks < 4; ks++) {
            bf16x8 pa = *(const bf16x8*)&Pw[lq * 136 + ks * 32 + quad * 8];
            o0 = __builtin_amdgcn_mfma_f32_16x16x32_bf16(pa, v0r[ks], o0, 0, 0, 0);
            o1 = __builtin_amdgcn_mfma_f32_16x16x32_bf16(pa, v1r[ks], o1, 0, 0, 0);
        }
#pragma unroll
        for (int r = 0; r < 4; r++) {
            Op[w * 528 + (quad * 4 + r) * 33 + lq]      = o0[r];
            Op[w * 528 + (quad * 4 + r) * 33 + 16 + lq] = o1[r];
        }

        // raw barrier: compiler fence + lgkm-only drain; prefetch stays live.
        __builtin_amdgcn_sched_barrier(0);
        asm volatile("s_waitcnt lgkmcnt(0)" ::: "memory");
        __builtin_amdgcn_s_barrier();
        __builtin_amdgcn_sched_barrier(0);

        // cross-wave reduce: normalized O write
        {
            const int t = tid >> 5, d = tid & 31;
            float s = 0.f, o = 0.f;
#pragma unroll
            for (int w2 = 0; w2 < 8; w2++) s += red[w2 * 16 + t];
#pragma unroll
            for (int w2 = 0; w2 < 8; w2++) o += Op[w2 * 528 + t * 33 + d];
            attnb[((size_t)(t0 + ts * 16 + t) * 4 + b) * 512 + (z * 8 + hh) * 32 + d] =
                (__bf16)(o / s);
        }

        // inv for this lane's rows (t = ts*16+lq) + avg fold from LDS P
        // (this wave's own slice; next overwrite is this wave's next P-write)
        float s_all = 0.f;
#pragma unroll
        for (int w2 = 0; w2 < 8; w2++) s_all += red[w2 * 16 + lq];
        const float inv = 1.0f / s_all;
#pragma unroll
        for (int j = 0; j < 8; j++) {
            bf16x4 pb = *(const bf16x4*)&Pw[lq * 136 + j * 16 + quad * 4];
#pragma unroll
            for (int r = 0; r < 4; r++)
                avg[j * 4 + r] += (float)pb[r] * inv;
        }
    };

    for (int hh = 0; hh < 8; hh++) {
        body(hh, 0, avg0);
        body(hh, 1, avg1);
    }

    // head-mean stores for both t-subtiles: z=0 fp32 direct, z=1 bf16 partial
#pragma unroll
    for (int ts = 0; ts < 2; ts++) {
        const float* avg = ts ? avg1 : avg0;
        const size_t rowbase = ((size_t)(b * 1024 + t0 + ts * 16 + lq) << 10) +
                               sbase + quad * 4;
        if (z == 0) {
            float* ap = avgf + rowbase;
#pragma unroll
            for (int j = 0; j < 8; j++) {
                f32x4 v = { avg[j * 4 + 0] * 0.0625f, avg[j * 4 + 1] * 0.0625f,
                            avg[j * 4 + 2] * 0.0625f, avg[j * 4 + 3] * 0.0625f };
                *(f32x4*)(ap + j * 16) = v;
            }
        } else {
            __bf16* pp = p1 + rowbase;
#pragma unroll
            for (int j = 0; j < 8; j++) {
                bf16x4 v;
                v[0] = (__bf16)(avg[j * 4 + 0] * 0.0625f);
                v[1] = (__bf16)(avg[j * 4 + 1] * 0.0625f);
                v[2] = (__bf16)(avg[j * 4 + 2] * 0.0625f);
                v[3] = (__bf16)(avg[j * 4 + 3] * 0.0625f);
                *(bf16x4*)(pp + j * 16) = v;
            }
        }
    }
}

// ---------------------------------------------------------------------------
extern "C" void kernel_launch(void* const* d_in, const int* in_sizes, int n_in,
                              void* d_out, int out_size, void* d_ws, size_t ws_size,
                              hipStream_t stream)
{
    const float* query     = (const float*)d_in[0];
    const float* attn_bias = (const float*)d_in[1];
    const int*   mask      = (const int*)d_in[2];
    const float* q_w       = (const float*)d_in[3];
    const float* q_b       = (const float*)d_in[4];
    const float* k_w       = (const float*)d_in[5];
    const float* k_b       = (const float*)d_in[6];
    const float* v_w       = (const float*)d_in[7];
    const float* v_b       = (const float*)d_in[8];
    const float* out_w     = (const float*)d_in[9];
    const float* out_b     = (const float*)d_in[10];

    float* out     = (float*)d_out;                 // [1024,4,512]
    float* avg_out = out + (size_t)2097152;         // [4,1024,1024]

    char* wsb = (char*)d_ws;
    __bf16* Wqb   = (__bf16*)(wsb);                         // 512 KB
    __bf16* Wkb   = (__bf16*)(wsb + ((size_t)512 << 10));
    __bf16* Wvb   = (__bf16*)(wsb + ((size_t)1 << 20));
    __bf16* Wob   = (__bf16*)(wsb + ((size_t)1 << 20) + ((size_t)512 << 10));
    __bf16* qTb   = (__bf16*)(wsb + ((size_t)2  << 20));    // 4 MB [64][1024][32]
    __bf16* kTb   = (__bf16*)(wsb + ((size_t)6  << 20));    // 4 MB [64][1024][32]
    __bf16* vTb   = (__bf16*)(wsb + ((size_t)10 << 20));    // 4 MB [64][32][1024]
    __bf16* attnb = (__bf16*)(wsb + ((size_t)14 << 20));    // 4 MB [4096][512]
    __bf16* p1    = (__bf16*)(wsb + ((size_t)18 << 20));    // 8 MB

    cvt_w<<<dim3(128, 4), dim3(256), 0, stream>>>(
        q_w, k_w, v_w, out_w, Wqb, Wkb, Wvb, Wob);

    qkv_proj<<<dim3(64, 4), dim3(256), 0, stream>>>(
        query, Wqb, Wkb, Wvb, q_b, k_b, v_b, qTb, kTb, vTb);

    attn_mfma<<<dim3(32, 4, 2), dim3(512), 0, stream>>>(
        qTb, kTb, vTb, attn_bias, mask, attnb, avg_out, p1);

    out_proj<<<dim3(64, 36), dim3(256), 0, stream>>>(
        attnb, Wob, out_b, out, avg_out, p1);
}